// Round 1
// baseline (156.658 us; speedup 1.0000x reference)
//
#include <hip/hip_runtime.h>
#include <cfloat>
#include <cmath>

#define N_NODES 20000
#define MAXD 32
#define F 128

// ---------------- stage 1: trimmed-mean aggregation ----------------

template <int SZ>
__device__ __forceinline__ void bitonic_sort(float (&k)[SZ]) {
#pragma unroll
  for (int size = 2; size <= SZ; size <<= 1) {
#pragma unroll
    for (int stride = size >> 1; stride > 0; stride >>= 1) {
#pragma unroll
      for (int i = 0; i < SZ; ++i) {
        int j = i ^ stride;
        if (j > i) {
          bool up = ((i & size) == 0);
          float a = k[i], b = k[j];
          float mn = fminf(a, b), mx = fmaxf(a, b);
          k[i] = up ? mn : mx;
          k[j] = up ? mx : mn;
        }
      }
    }
  }
}

// extract element at (uniform) position p from a statically-indexed register array
template <int SZ>
__device__ __forceinline__ float extract_pos(const float (&k)[SZ], int p) {
  float sel[SZ];
#pragma unroll
  for (int i = 0; i < SZ; ++i) sel[i] = k[i];
#pragma unroll
  for (int w = SZ >> 1; w >= 1; w >>= 1) {
    bool take = (p & w) != 0;
#pragma unroll
    for (int i = 0; i < w; ++i) sel[i] = take ? sel[i + w] : sel[i];
  }
  return sel[0];
}

// Exact trimmed sum: sum of payloads (key*norm_src) whose STABLE rank (key asc,
// ties by slot index — matches jnp.argsort stable) lies in [b, n-b).
template <int SZ>
__device__ __forceinline__ float trimmed_sum(const float* __restrict__ h,
                                             const float* __restrict__ norm,
                                             const int* __restrict__ nbr_row,
                                             int n, int f, int b) {
  float key[SZ];
  float nrm[SZ];  // block-uniform -> SGPRs
#pragma unroll
  for (int d = 0; d < SZ; ++d) {
    if (d < n) {  // uniform branch (n is block-uniform)
      int src = nbr_row[d];       // scalar load
      nrm[d] = norm[src];         // scalar load
      key[d] = h[src * F + f];    // vector load, coalesced 256B/wave
    } else {
      nrm[d] = 0.f;
      key[d] = FLT_MAX;           // pads sort past all valid keys
    }
  }

  float sk[SZ];
#pragma unroll
  for (int d = 0; d < SZ; ++d) sk[d] = key[d];
  bitonic_sort<SZ>(sk);

  const float lo = extract_pos<SZ>(sk, b);          // key at rank b
  const float hi = extract_pos<SZ>(sk, n - b - 1);  // key at rank n-b-1

  int c_lt_lo = 0, c_lt_hi = 0;
#pragma unroll
  for (int d = 0; d < SZ; ++d) {
    c_lt_lo += (key[d] < lo) ? 1 : 0;
    c_lt_hi += (key[d] < hi) ? 1 : 0;
  }

  // Pass 2: strictly-between keys are always kept; keys equal to lo/hi are kept
  // based on their exact stable rank (c_lt + running-equal-prefix).
  float sum = 0.f;
  int run_lo = 0, run_hi = 0;
  const int nb = n - b;
#pragma unroll
  for (int d = 0; d < SZ; ++d) {
    const float kd = key[d];
    const float m = kd * nrm[d];  // pads: FLT_MAX*0 = 0 (finite, safe)
    const bool eql = (kd == lo);
    const bool eqh = (kd == hi);
    const bool lh = (lo < hi);
    const bool btw = (kd > lo) & (kd < hi);
    const int r_lo = c_lt_lo + run_lo;  // stable rank if kd==lo
    const int r_hi = c_lt_hi + run_hi;  // stable rank if kd==hi
    const bool inc = btw
                   | (eql & (r_lo >= b) & (lh | (r_lo < nb)))  // lo==hi needs both bounds
                   | (lh & eqh & (r_hi < nb));
    sum += inc ? m : 0.f;
    run_lo += eql ? 1 : 0;
    run_hi += eqh ? 1 : 0;
  }
  return sum;
}

__global__ __launch_bounds__(128) void gcn_stage1(const float* __restrict__ h,
                                                  const float* __restrict__ norm,
                                                  const int* __restrict__ nbr,
                                                  const int* __restrict__ deg,
                                                  float* __restrict__ accum) {
  const int i = blockIdx.x;
  const int f = threadIdx.x;
  const int n = deg[i];            // block-uniform
  const float ni = norm[i];
  const float hif = h[i * F + f];
  const int idx = i * F + f;

  if (n <= 3) {  // N_NEIGH_THRESHOLD branch: accum = n * (h*norm) * norm
    accum[idx] = (float)n * hif * ni * ni;
    return;
  }

  // b = max(min(n//2 - (1 - n%2), floor_f32(n*0.45f)), 1)   (fp32 floor matches jnp)
  int b = n / 2 - (1 - (n & 1));
  int bcap = (int)floorf((float)n * 0.45f);
  b = b < bcap ? b : bcap;
  b = b > 1 ? b : 1;

  const int* nbr_row = nbr + i * MAXD;
  float ts;
  if (n <= 4)       ts = trimmed_sum<4>(h, norm, nbr_row, n, f, b);
  else if (n <= 8)  ts = trimmed_sum<8>(h, norm, nbr_row, n, f, b);
  else if (n <= 16) ts = trimmed_sum<16>(h, norm, nbr_row, n, f, b);
  else              ts = trimmed_sum<32>(h, norm, nbr_row, n, f, b);

  // accum_med = (trimmed_sum + self0 * 2b) * norm ; self0 = h*norm
  accum[idx] = (ts + hif * ni * (float)(2 * b)) * ni;
}

// ---------------- stage 2: out = relu(accum @ W + bias) ----------------
// 256 threads, 32 rows/block, W staged in LDS in two 64-row halves (32KB each),
// A tile padded to stride 132 (breaks the stride-128 bank pattern, keeps 16B align).

__global__ __launch_bounds__(256) void gcn_gemm(const float* __restrict__ A,
                                                const float* __restrict__ W,
                                                const float* __restrict__ bias,
                                                float* __restrict__ out) {
  __shared__ float Ws[64 * F];    // 32 KB (one K-half of W)
  __shared__ float As[32 * 132];  // 16.9 KB
  const int t = threadIdx.x;
  const int row0 = blockIdx.x * 32;

  // stage A tile: 32 rows x 128 cols = 1024 float4
#pragma unroll
  for (int u = 0; u < 4; ++u) {
    int idx = t + u * 256;
    int r = idx >> 5, c4 = idx & 31;
    float4 v = *(const float4*)(A + (row0 + r) * F + c4 * 4);
    *(float4*)(As + r * 132 + c4 * 4) = v;
  }

  const int tx = t & 31, ty = t >> 5;
  float acc[4][4];
#pragma unroll
  for (int r = 0; r < 4; ++r)
#pragma unroll
    for (int c = 0; c < 4; ++c) acc[r][c] = 0.f;

#pragma unroll
  for (int kc = 0; kc < 2; ++kc) {
    __syncthreads();  // As ready (kc=0) / previous Ws reads done (kc=1)
#pragma unroll
    for (int u = 0; u < 8; ++u) {
      int idx = t + u * 256;  // 0..2047 float4s
      *(float4*)(Ws + idx * 4) = *(const float4*)(W + kc * 64 * F + idx * 4);
    }
    __syncthreads();
#pragma unroll 4
    for (int k = 0; k < 64; ++k) {
      float4 w = *(const float4*)(Ws + k * F + tx * 4);
      float a0 = As[(ty * 4 + 0) * 132 + kc * 64 + k];
      float a1 = As[(ty * 4 + 1) * 132 + kc * 64 + k];
      float a2 = As[(ty * 4 + 2) * 132 + kc * 64 + k];
      float a3 = As[(ty * 4 + 3) * 132 + kc * 64 + k];
      acc[0][0] += a0 * w.x; acc[0][1] += a0 * w.y; acc[0][2] += a0 * w.z; acc[0][3] += a0 * w.w;
      acc[1][0] += a1 * w.x; acc[1][1] += a1 * w.y; acc[1][2] += a1 * w.z; acc[1][3] += a1 * w.w;
      acc[2][0] += a2 * w.x; acc[2][1] += a2 * w.y; acc[2][2] += a2 * w.z; acc[2][3] += a2 * w.w;
      acc[3][0] += a3 * w.x; acc[3][1] += a3 * w.y; acc[3][2] += a3 * w.z; acc[3][3] += a3 * w.w;
    }
  }

  float4 bv = *(const float4*)(bias + tx * 4);
#pragma unroll
  for (int r = 0; r < 4; ++r) {
    float4 o;
    o.x = fmaxf(acc[r][0] + bv.x, 0.f);
    o.y = fmaxf(acc[r][1] + bv.y, 0.f);
    o.z = fmaxf(acc[r][2] + bv.z, 0.f);
    o.w = fmaxf(acc[r][3] + bv.w, 0.f);
    *(float4*)(out + (row0 + ty * 4 + r) * F + tx * 4) = o;
  }
}

extern "C" void kernel_launch(void* const* d_in, const int* in_sizes, int n_in,
                              void* d_out, int out_size, void* d_ws, size_t ws_size,
                              hipStream_t stream) {
  const float* h = (const float*)d_in[0];
  const float* norm = (const float*)d_in[1];
  const float* weight = (const float*)d_in[2];
  const float* bias = (const float*)d_in[3];
  const int* nbr = (const int*)d_in[4];
  const int* deg = (const int*)d_in[5];
  float* out = (float*)d_out;
  float* accum = (float*)d_ws;  // 20000*128*4 = 10.24 MB scratch

  gcn_stage1<<<N_NODES, 128, 0, stream>>>(h, norm, nbr, deg, accum);
  gcn_gemm<<<N_NODES / 32, 256, 0, stream>>>(accum, weight, bias, out);
}